// Round 1
// 135.236 us; speedup vs baseline: 1.0145x; 1.0145x over previous
//
#include <hip/hip_runtime.h>
#include <hip/hip_bf16.h>

#define DI __device__ __forceinline__

typedef __attribute__((ext_vector_type(8))) short bf16x8;   // 8 bf16 = 4 VGPRs (MFMA A/B frag)
typedef __attribute__((ext_vector_type(4))) short s16x4;    // 4 bf16 = 8 B (ds_write_b64)
typedef __attribute__((ext_vector_type(4))) float f32x4;    // MFMA C/D frag

constexpr int HW = 4096;
constexpr int SAS = 72;            // sA ic-stride (36 dwords)

// ---- workspace layout (bytes), all 16B aligned ----
constexpr size_t OFF_N1   = 0;                       // bf16 NHWC relu-able n1   16 MB
constexpr size_t OFF_P3F  = 16777216;                // f32 frag-layout p3       33.5 MB
constexpr size_t OFF_WB3  = OFF_P3F + 33554432;      // bf16 [3][9][64oc][64ic]
constexpr size_t OFF_WB1  = OFF_WB3 + 221184;        // bf16 [2][64oc][64ic]
constexpr size_t OFF_BIAS = OFF_WB1 + 16384;         // f32 [5][64]
constexpr size_t OFF_CC   = OFF_BIAS + 1280;         // int[2]

DI int argmax8(const float* __restrict__ a) {
    int best = 0; float bv = a[0];
#pragma unroll
    for (int i = 1; i < 8; ++i) { float v = a[i]; if (v > bv) { bv = v; best = i; } }
    return best;
}

DI short f2bf(float v) {   // fp32 -> bf16 bits (RNE)
    __hip_bfloat16 h = __float2bfloat16(v);
    return __builtin_bit_cast(short, h);
}

// ---------------------------------------------------------------------------
// prep: c1,c2; weights -> bf16 [edge][kpos][oc][ic] frag order, BN scale +
// channel masks folded; per-edge bias (out-masked). Tiny kernel (~3 us).
// ---------------------------------------------------------------------------
__global__ __launch_bounds__(256) void prep_kernel(
    const float* __restrict__ w3, const float* __restrict__ w1,
    const float* __restrict__ bn, const float* __restrict__ a1,
    const float* __restrict__ a2, char* __restrict__ ws) {
    short* __restrict__ wb3  = (short*)(ws + OFF_WB3);
    short* __restrict__ wb1  = (short*)(ws + OFF_WB1);
    float* __restrict__ bias = (float*)(ws + OFF_BIAS);
    int*   __restrict__ cc   = (int*)(ws + OFF_CC);
    const int c1 = 8 * (argmax8(a1) + 1);
    const int c2 = 8 * (argmax8(a2) + 1);

    const int idx = blockIdx.x * 256 + threadIdx.x;
    if (idx < 110592) {                       // wb3 flat = ((e*9+kp)*64+oc)*64+ic
        const int e = idx / 36864, rem = idx % 36864;
        const int kp = rem >> 12, oc = (rem >> 6) & 63, ic = rem & 63;
        const int bnrow = (e == 0) ? 0 : (e == 1) ? 1 : 3;
        const float g = bn[(bnrow * 4 + 0) * 64 + oc];
        const float v = bn[(bnrow * 4 + 3) * 64 + oc];
        const float s = g * rsqrtf(v + 1e-5f);
        const float wv = w3[((e * 64 + oc) * 64 + ic) * 9 + kp];
        wb3[idx] = (oc < c2 && ic < c1) ? f2bf(wv * s) : (short)0;
    } else if (idx < 118784) {                // wb1 flat = (e*64+oc)*64+ic
        const int j = idx - 110592;
        const int e = j >> 12, oc = (j >> 6) & 63, ic = j & 63;
        const int bnrow = (e == 0) ? 2 : 4;
        const float g = bn[(bnrow * 4 + 0) * 64 + oc];
        const float v = bn[(bnrow * 4 + 3) * 64 + oc];
        const float s = g * rsqrtf(v + 1e-5f);
        wb1[j] = (oc < c2 && ic < c1) ? f2bf(w1[(e * 64 + oc) * 64 + ic] * s) : (short)0;
    } else if (idx < 119104) {                // bias
        const int j = idx - 118784;
        const int e = j >> 6, oc = j & 63;
        const float g = bn[(e * 4 + 0) * 64 + oc];
        const float b = bn[(e * 4 + 1) * 64 + oc];
        const float m = bn[(e * 4 + 2) * 64 + oc];
        const float v = bn[(e * 4 + 3) * 64 + oc];
        bias[j] = (oc < c2) ? (b - m * g * rsqrtf(v + 1e-5f)) : 0.f;
    } else if (idx == 119104) {
        cc[0] = c1; cc[1] = c2;
    }
}

// ---------------------------------------------------------------------------
// stage sA (6 rows x 66 cols x live ic) DIRECTLY from fp32 NCHW x with fused
// relu + bf16 convert + transpose.
// ---------------------------------------------------------------------------
DI void stage_sA_from_x(const float* __restrict__ x, short* __restrict__ sA,
                        int n, int y0, int SGm, int t) {
    const int w = t >> 6, l = t & 63;
    if (t < 96) {   // zero halo cols c=0 and c=65: (r<6, chp<2, sg<8)
        const int r = t >> 4, chp = (t >> 3) & 1, sg = t & 7;
        *(bf16x8*)(&sA[(r * 66 + chp * 65) * SAS + sg * 8]) = (bf16x8)0;
    }
#pragma unroll 1
    for (int u = w; u < 48; u += 4) {          // (row r = u>>3, ic-group icg = u&7)
        const int r = u >> 3, icg = u & 7;
        if (icg < SGm) {                        // wave-uniform ic cull
            const int gy = y0 + r - 1;
            const float* __restrict__ src = x + (((size_t)n * 64 + icg * 8) * 64 + gy) * 64 + l;
            bf16x8 pk = (bf16x8)0;
            if ((unsigned)gy < 64u) {           // wave-uniform y-halo check
#pragma unroll
                for (int j = 0; j < 8; ++j)
                    pk[j] = f2bf(fmaxf(src[j * HW], 0.f));
            }
            *(bf16x8*)(&sA[(r * 66 + l + 1) * SAS + icg * 8]) = pk;
        }
    }
}

// stage sA from a bf16 NHWC tensor (K2: n1 with halo)
DI void stage_sA(const short* __restrict__ src, short* __restrict__ sA,
                 int n, int y0, int SGm, int t) {
    for (int idx = t; idx < 6 * 66 * 8; idx += 256) {
        const int r = idx / 528, rem = idx - r * 528, c = rem >> 3, sg = rem & 7;
        if (sg < SGm) {
            const int gy = y0 + r - 1, gx = c - 1;
            bf16x8 v = 0;
            if ((unsigned)gy < 64u && (unsigned)gx < 64u)
                v = *(const bf16x8*)(src + ((n * 64 + gy) * 64 + gx) * 64 + sg * 8);
            *(bf16x8*)(&sA[(r * 66 + c) * SAS + sg * 8]) = v;
        }
    }
}

// coalesced store of one 64-px row (sA cols 1..64, all 64 ch) to NHWC global.
DI void store_row_from_sA(const short* __restrict__ sA, int row,
                          short* __restrict__ dst, int l) {
#pragma unroll
    for (int i = 0; i < 8; ++i) {
        const int c = i * 8 + (l >> 3), sg = l & 7;
        *(bf16x8*)(dst + c * 64 + sg * 8) =
            *(const bf16x8*)(&sA[(row * 66 + c + 1) * SAS + sg * 8]);
    }
}

// ---------------------------------------------------------------------------
// K1: fused mid. Dual conv3 (e0->acc1, e1->acc2) with SWAPPED mfma operands
// (mfma(W,A) == transposed D with identical fragment data): lane holds
// px = mt*16+lm (fixed), oc = nt*16+q*4+r (consecutive) -> epilogue writes
// are ds_write_b64 of 4 consecutive oc instead of 4 scalar b16 writes.
// conv1_e1 stays in NORMAL order so acc3 (px consecutive per lane) is stored
// straight to global as fp32 lane-indexed f32x4 frags (no LDS, no bf16).
// ---------------------------------------------------------------------------
__global__ __launch_bounds__(256, 2) void fused_mid_kernel(
    const float* __restrict__ x, const char* __restrict__ ws,
    short* __restrict__ n1out, float* __restrict__ p3out) {
    __shared__ __align__(16) short sA[6 * 66 * SAS];   // 55.7 KB
    const int t = threadIdx.x, w = t >> 6, l = t & 63, lm = l & 15, q = l >> 4;
    const int y0 = blockIdx.x * 4, n = blockIdx.y;
    const int* cc = (const int*)(ws + OFF_CC);
    const int c1 = __builtin_amdgcn_readfirstlane(cc[0]);
    const int c2 = __builtin_amdgcn_readfirstlane(cc[1]);
    const int SGm = (c1 > 32) ? 8 : 4;
    const float* __restrict__ bias = (const float*)(ws + OFF_BIAS);
    const short* __restrict__ WBe0 = (const short*)(ws + OFF_WB3);
    const short* __restrict__ WBe1 = WBe0 + 36864;
    const short* __restrict__ W1e0 = (const short*)(ws + OFF_WB1);
    const short* __restrict__ W1e1 = W1e0 + 4096;

    f32x4 acc1[4][4], acc2[4][4];
#pragma unroll
    for (int i = 0; i < 4; ++i)
#pragma unroll
        for (int j = 0; j < 4; ++j) { acc1[i][j] = 0.f; acc2[i][j] = 0.f; }

    stage_sA_from_x(x, sA, n, y0, SGm, t);
    __syncthreads();

    // ---- dual conv3 K-loop (barrier-free, sA read-only), SWAPPED operands ----
    {
        const short* __restrict__ W0 = WBe0;
        const short* __restrict__ W1 = WBe1;
#pragma unroll 1
        for (int ky = 0; ky < 3; ++ky) {
#pragma unroll 1
            for (int kx = 0; kx < 3; ++kx) {
#pragma unroll
                for (int kc = 0; kc < 2; ++kc) {
                    if (kc == 0 || c1 > 32) {
                        bf16x8 af[4], b0[4], b1[4];
#pragma unroll
                        for (int nt = 0; nt < 4; ++nt)
                            if (nt * 16 < c2) {
                                b0[nt] = *(const bf16x8*)(W0 + (nt * 16 + lm) * 64 + kc * 32 + q * 8);
                                b1[nt] = *(const bf16x8*)(W1 + (nt * 16 + lm) * 64 + kc * 32 + q * 8);
                            }
#pragma unroll
                        for (int mt = 0; mt < 4; ++mt)
                            af[mt] = *(const bf16x8*)(&sA[((w + ky) * 66 + (mt * 16 + lm + kx)) * SAS + kc * 32 + q * 8]);
#pragma unroll
                        for (int nt = 0; nt < 4; ++nt)
                            if (nt * 16 < c2) {
#pragma unroll
                                for (int mt = 0; mt < 4; ++mt) {
                                    acc1[mt][nt] = __builtin_amdgcn_mfma_f32_16x16x32_bf16(b0[nt], af[mt], acc1[mt][nt], 0, 0, 0);
                                    acc2[mt][nt] = __builtin_amdgcn_mfma_f32_16x16x32_bf16(b1[nt], af[mt], acc2[mt][nt], 0, 0, 0);
                                }
                            }
                    }
                }
                W0 += 4096; W1 += 4096;
            }
        }
    }

    __syncthreads();   // all waves done reading stage-1 sA; rows become wave-private

    const int y = y0 + w;
    short* __restrict__ n1row = n1out + (size_t)((n * 64 + y) * 64) * 64;

    // epi1: n1 = relu(acc1 + b0) -> own sA row; swapped layout: lane owns
    // px = mt*16+lm, oc = nt*16+q*4+r (4 consecutive shorts -> one b64 write)
#pragma unroll
    for (int nt = 0; nt < 4; ++nt) {
        const f32x4 bv = *(const f32x4*)(bias + nt * 16 + q * 4);
#pragma unroll
        for (int mt = 0; mt < 4; ++mt) {
            s16x4 pk;
#pragma unroll
            for (int r = 0; r < 4; ++r)
                pk[r] = f2bf(fmaxf(acc1[mt][nt][r] + bv[r], 0.f));
            *(s16x4*)(&sA[((w + 1) * 66 + mt * 16 + lm + 1) * SAS + nt * 16 + q * 4]) = pk;
        }
    }
    store_row_from_sA(sA, w + 1, n1row, l);

    // conv1_e0(n1) += acc2 (own row), swapped
#pragma unroll
    for (int kc = 0; kc < 2; ++kc) {
        if (kc == 0 || c1 > 32) {
            bf16x8 af[4], bfr[4];
#pragma unroll
            for (int mt = 0; mt < 4; ++mt)
                af[mt] = *(const bf16x8*)(&sA[((w + 1) * 66 + (mt * 16 + lm + 1)) * SAS + kc * 32 + q * 8]);
#pragma unroll
            for (int nt = 0; nt < 4; ++nt)
                if (nt * 16 < c2)
                    bfr[nt] = *(const bf16x8*)(W1e0 + (nt * 16 + lm) * 64 + kc * 32 + q * 8);
#pragma unroll
            for (int nt = 0; nt < 4; ++nt)
                if (nt * 16 < c2) {
#pragma unroll
                    for (int mt = 0; mt < 4; ++mt)
                        acc2[mt][nt] = __builtin_amdgcn_mfma_f32_16x16x32_bf16(bfr[nt], af[mt], acc2[mt][nt], 0, 0, 0);
                }
        }
    }

    // epi2: n2 = relu(acc2 + b1 + b2) -> own sA row (overwrites n1 row; n1
    // already stored to global and consumed by conv1_e0 above)
#pragma unroll
    for (int nt = 0; nt < 4; ++nt) {
        const f32x4 b1v = *(const f32x4*)(bias + 64 + nt * 16 + q * 4);
        const f32x4 b2v = *(const f32x4*)(bias + 128 + nt * 16 + q * 4);
#pragma unroll
        for (int mt = 0; mt < 4; ++mt) {
            s16x4 pk;
#pragma unroll
            for (int r = 0; r < 4; ++r)
                pk[r] = f2bf(fmaxf(acc2[mt][nt][r] + b1v[r] + b2v[r], 0.f));
            *(s16x4*)(&sA[((w + 1) * 66 + mt * 16 + lm + 1) * SAS + nt * 16 + q * 4]) = pk;
        }
    }

    // conv1_e1(n2) -> acc3, NORMAL operand order (lane: oc=nt*16+lm fixed,
    // px=mt*16+q*4+r consecutive) -> direct coalesced f32x4 frag store.
    {
        f32x4 acc3[4][4];
#pragma unroll
        for (int i = 0; i < 4; ++i)
#pragma unroll
            for (int j = 0; j < 4; ++j) acc3[i][j] = 0.f;
#pragma unroll
        for (int kc = 0; kc < 2; ++kc) {
            if (kc == 0 || c1 > 32) {
                bf16x8 af[4], bfr[4];
#pragma unroll
                for (int mt = 0; mt < 4; ++mt)
                    af[mt] = *(const bf16x8*)(&sA[((w + 1) * 66 + (mt * 16 + lm + 1)) * SAS + kc * 32 + q * 8]);
#pragma unroll
                for (int nt = 0; nt < 4; ++nt)
                    if (nt * 16 < c2)
                        bfr[nt] = *(const bf16x8*)(W1e1 + (nt * 16 + lm) * 64 + kc * 32 + q * 8);
#pragma unroll
                for (int nt = 0; nt < 4; ++nt)
                    if (nt * 16 < c2) {
#pragma unroll
                        for (int mt = 0; mt < 4; ++mt)
                            acc3[mt][nt] = __builtin_amdgcn_mfma_f32_16x16x32_bf16(af[mt], bfr[nt], acc3[mt][nt], 0, 0, 0);
                    }
            }
        }
        // epi3: p3 = acc3 + b4, stored fp32 in frag layout:
        // chunk [n][y][nt*4+mt] of 1 KB, lane l's 4 floats at offset l*4.
        float* __restrict__ p3c = p3out + (size_t)(n * 64 + y) * 4096;
#pragma unroll
        for (int nt = 0; nt < 4; ++nt) {
            const float bvs = bias[256 + nt * 16 + lm];
#pragma unroll
            for (int mt = 0; mt < 4; ++mt) {
                f32x4 v = acc3[mt][nt];
#pragma unroll
                for (int r = 0; r < 4; ++r) v[r] += bvs;
                *(f32x4*)(p3c + (nt * 4 + mt) * 256 + l * 4) = v;
            }
        }
    }
}

// ---------------------------------------------------------------------------
// K2: d_out = x + conv3_e2(n1) + p3. Normal mfma order -> lane holds 4
// consecutive x-positions per acc frag, so the NCHW fp32 output is stored
// directly as f32x4 (fused with skip-add and the lane-matched p3 frag read).
// No LDS epilogue, no extra barriers.
// ---------------------------------------------------------------------------
__global__ __launch_bounds__(256, 2) void final_conv_kernel(
    const short* __restrict__ n1in, const char* __restrict__ ws,
    const float* __restrict__ skip, float* __restrict__ outp) {
    __shared__ __align__(16) short sA[6 * 66 * SAS];
    const int t = threadIdx.x, w = t >> 6, l = t & 63, lm = l & 15, q = l >> 4;
    const int y0 = blockIdx.x * 4, n = blockIdx.y;
    const int* cc = (const int*)(ws + OFF_CC);
    const int c1 = __builtin_amdgcn_readfirstlane(cc[0]);
    const int c2 = __builtin_amdgcn_readfirstlane(cc[1]);
    const int SGm = (c1 > 32) ? 8 : 4;
    const float* __restrict__ bias3 = (const float*)(ws + OFF_BIAS) + 192;
    const short* __restrict__ WBe2 = (const short*)(ws + OFF_WB3) + 2 * 36864;
    const float* __restrict__ p3f = (const float*)(ws + OFF_P3F);

    f32x4 acc[4][4];
#pragma unroll
    for (int i = 0; i < 4; ++i)
#pragma unroll
        for (int j = 0; j < 4; ++j) acc[i][j] = 0.f;

    stage_sA(n1in, sA, n, y0, SGm, t);
    __syncthreads();

    {
        const short* __restrict__ Wk = WBe2;
#pragma unroll 1
        for (int ky = 0; ky < 3; ++ky) {
#pragma unroll 1
            for (int kx = 0; kx < 3; ++kx) {
#pragma unroll
                for (int kc = 0; kc < 2; ++kc) {
                    if (kc == 0 || c1 > 32) {
                        bf16x8 af[4], bfr[4];
#pragma unroll
                        for (int nt = 0; nt < 4; ++nt)
                            if (nt * 16 < c2)
                                bfr[nt] = *(const bf16x8*)(Wk + (nt * 16 + lm) * 64 + kc * 32 + q * 8);
#pragma unroll
                        for (int mt = 0; mt < 4; ++mt)
                            af[mt] = *(const bf16x8*)(&sA[((w + ky) * 66 + (mt * 16 + lm + kx)) * SAS + kc * 32 + q * 8]);
#pragma unroll
                        for (int nt = 0; nt < 4; ++nt)
                            if (nt * 16 < c2) {
#pragma unroll
                                for (int mt = 0; mt < 4; ++mt)
                                    acc[mt][nt] = __builtin_amdgcn_mfma_f32_16x16x32_bf16(af[mt], bfr[nt], acc[mt][nt], 0, 0, 0);
                            }
                    }
                }
                Wk += 4096;
            }
        }
    }

    // ---- direct epilogue: acc + bias3 + p3(frag, lane-matched) + skip ----
    const int y = y0 + w;
    const float* __restrict__ p3c = p3f + (size_t)(n * 64 + y) * 4096;
#pragma unroll
    for (int nt = 0; nt < 4; ++nt) {
        const int oc = nt * 16 + lm;
        const float bvs = bias3[oc];
#pragma unroll
        for (int mt = 0; mt < 4; ++mt) {
            const f32x4 p = *(const f32x4*)(p3c + (nt * 4 + mt) * 256 + l * 4);
            const size_t ob = (((size_t)n * 64 + oc) * 64 + y) * 64 + mt * 16 + q * 4;
            const f32x4 s = *(const f32x4*)(skip + ob);
            f32x4 v;
#pragma unroll
            for (int r = 0; r < 4; ++r) v[r] = acc[mt][nt][r] + bvs + p[r] + s[r];
            *(f32x4*)(outp + ob) = v;   // oc>=c2: acc=bias=p3=0 -> skip only
        }
    }
}

// ---------------------------------------------------------------------------
extern "C" void kernel_launch(void* const* d_in, const int* in_sizes, int n_in,
                              void* d_out, int out_size, void* d_ws, size_t ws_size,
                              hipStream_t stream) {
    (void)in_sizes; (void)n_in; (void)out_size; (void)ws_size;
    const float* x  = (const float*)d_in[0];
    const float* a1 = (const float*)d_in[1];
    const float* a2 = (const float*)d_in[2];
    const float* w3 = (const float*)d_in[3];
    const float* w1 = (const float*)d_in[4];
    const float* bn = (const float*)d_in[5];
    char* ws = (char*)d_ws;

    short* n1  = (short*)(ws + OFF_N1);
    float* p3f = (float*)(ws + OFF_P3F);

    prep_kernel<<<466, 256, 0, stream>>>(w3, w1, bn, a1, a2, ws);
    const dim3 gc(16, 32);   // y-tiles, n
    fused_mid_kernel<<<gc, 256, 0, stream>>>(x, ws, n1, p3f);
    final_conv_kernel<<<gc, 256, 0, stream>>>(n1, ws, x, (float*)d_out);
}

// Round 2
// 124.735 us; speedup vs baseline: 1.0999x; 1.0842x over previous
//
#include <hip/hip_runtime.h>
#include <hip/hip_bf16.h>

#define DI __device__ __forceinline__
#define MFMA __builtin_amdgcn_mfma_f32_16x16x32_bf16

typedef __attribute__((ext_vector_type(8))) short bf16x8;   // 8 bf16 = 4 VGPRs (MFMA A/B frag)
typedef __attribute__((ext_vector_type(4))) short s16x4;    // 4 bf16 = 8 B (ds_write_b64)
typedef __attribute__((ext_vector_type(4))) float f32x4;    // MFMA C/D frag

constexpr int HW = 4096;
constexpr int SAS = 72;            // ic-stride in shorts (144 B -> 2-way banks, free)

// ---- workspace layout (bytes): weights only now (~240 KB) ----
constexpr size_t OFF_WB3  = 0;                       // bf16 [3][9][64oc][64ic]
constexpr size_t OFF_WB1  = OFF_WB3 + 221184;        // bf16 [2][64oc][64ic]
constexpr size_t OFF_BIAS = OFF_WB1 + 16384;         // f32 [5][64]
constexpr size_t OFF_CC   = OFF_BIAS + 1280;         // int[2]

// ---- LDS layout (short offsets), dynamic 149,760 B ----
constexpr int FR    = 66 * SAS;          // 4752 shorts per frame/slot row
constexpr int L_N2  = 8 * FR;            // n2 scratch: 4 rows x 64 x SAS
constexpr int N2R   = 64 * SAS;          // 4608 shorts per n2/p3 row
constexpr int L_P3  = L_N2 + 4 * N2R;    // p3 exchange: 4 rows x 64oc x SAS
constexpr int L_TOT = L_P3 + 4 * N2R;    // 74880 shorts = 149760 B

DI int argmax8(const float* __restrict__ a) {
    int best = 0; float bv = a[0];
#pragma unroll
    for (int i = 1; i < 8; ++i) { float v = a[i]; if (v > bv) { bv = v; best = i; } }
    return best;
}

DI short f2bf(float v) {
    __hip_bfloat16 h = __float2bfloat16(v);
    return __builtin_bit_cast(short, h);
}

DI float bf2f(short s) {
    return __bfloat162float(__builtin_bit_cast(__hip_bfloat16, s));
}

// ---------------------------------------------------------------------------
// prep: identical to previous rounds (offsets shifted).
// ---------------------------------------------------------------------------
__global__ __launch_bounds__(256) void prep_kernel(
    const float* __restrict__ w3, const float* __restrict__ w1,
    const float* __restrict__ bn, const float* __restrict__ a1,
    const float* __restrict__ a2, char* __restrict__ ws) {
    short* __restrict__ wb3  = (short*)(ws + OFF_WB3);
    short* __restrict__ wb1  = (short*)(ws + OFF_WB1);
    float* __restrict__ bias = (float*)(ws + OFF_BIAS);
    int*   __restrict__ cc   = (int*)(ws + OFF_CC);
    const int c1 = 8 * (argmax8(a1) + 1);
    const int c2 = 8 * (argmax8(a2) + 1);

    const int idx = blockIdx.x * 256 + threadIdx.x;
    if (idx < 110592) {                       // wb3 flat = ((e*9+kp)*64+oc)*64+ic
        const int e = idx / 36864, rem = idx % 36864;
        const int kp = rem >> 12, oc = (rem >> 6) & 63, ic = rem & 63;
        const int bnrow = (e == 0) ? 0 : (e == 1) ? 1 : 3;
        const float g = bn[(bnrow * 4 + 0) * 64 + oc];
        const float v = bn[(bnrow * 4 + 3) * 64 + oc];
        const float s = g * rsqrtf(v + 1e-5f);
        const float wv = w3[((e * 64 + oc) * 64 + ic) * 9 + kp];
        wb3[idx] = (oc < c2 && ic < c1) ? f2bf(wv * s) : (short)0;
    } else if (idx < 118784) {                // wb1 flat = (e*64+oc)*64+ic
        const int j = idx - 110592;
        const int e = j >> 12, oc = (j >> 6) & 63, ic = j & 63;
        const int bnrow = (e == 0) ? 2 : 4;
        const float g = bn[(bnrow * 4 + 0) * 64 + oc];
        const float v = bn[(bnrow * 4 + 3) * 64 + oc];
        const float s = g * rsqrtf(v + 1e-5f);
        wb1[j] = (oc < c2 && ic < c1) ? f2bf(w1[(e * 64 + oc) * 64 + ic] * s) : (short)0;
    } else if (idx < 119104) {                // bias
        const int j = idx - 118784;
        const int e = j >> 6, oc = j & 63;
        const float g = bn[(e * 4 + 0) * 64 + oc];
        const float b = bn[(e * 4 + 1) * 64 + oc];
        const float m = bn[(e * 4 + 2) * 64 + oc];
        const float v = bn[(e * 4 + 3) * 64 + oc];
        bias[j] = (oc < c2) ? (b - m * g * rsqrtf(v + 1e-5f)) : 0.f;
    } else if (idx == 119104) {
        cc[0] = c1; cc[1] = c2;
    }
}

// ---------------------------------------------------------------------------
// conv helpers (all loops compile-time; wave-uniform channel culls)
// ---------------------------------------------------------------------------
// 3x3 conv, one row, SWAPPED operands (lane: px=mt*16+lm, oc=nt*16+q*4+r)
DI void conv3_sw1(const short* __restrict__ sA, int f0,
                  const short* __restrict__ WB, int c1, int c2,
                  int lm, int q, f32x4 (&acc)[4][4]) {
    const short* __restrict__ W = WB;
#pragma unroll 1
    for (int ky = 0; ky < 3; ++ky)
#pragma unroll 1
        for (int kx = 0; kx < 3; ++kx) {
#pragma unroll
            for (int kc = 0; kc < 2; ++kc)
                if (kc == 0 || c1 > 32) {
                    bf16x8 af[4], bfr[4];
#pragma unroll
                    for (int nt = 0; nt < 4; ++nt)
                        if (nt * 16 < c2)
                            bfr[nt] = *(const bf16x8*)(W + (nt * 16 + lm) * 64 + kc * 32 + q * 8);
#pragma unroll
                    for (int mt = 0; mt < 4; ++mt)
                        af[mt] = *(const bf16x8*)(&sA[((f0 + ky) * 66 + mt * 16 + lm + kx) * SAS + kc * 32 + q * 8]);
#pragma unroll
                    for (int nt = 0; nt < 4; ++nt)
                        if (nt * 16 < c2)
#pragma unroll
                            for (int mt = 0; mt < 4; ++mt)
                                acc[mt][nt] = MFMA(bfr[nt], af[mt], acc[mt][nt], 0, 0, 0);
                }
            W += 4096;
        }
}

// 3x3 conv, TWO rows sharing weight frags, swapped (e1 waves)
DI void conv3_sw2(const short* __restrict__ sA, int f0a, int f0b,
                  const short* __restrict__ WB, int c1, int c2,
                  int lm, int q, f32x4 (&accA)[4][4], f32x4 (&accB)[4][4]) {
    const short* __restrict__ W = WB;
#pragma unroll 1
    for (int ky = 0; ky < 3; ++ky)
#pragma unroll 1
        for (int kx = 0; kx < 3; ++kx) {
#pragma unroll
            for (int kc = 0; kc < 2; ++kc)
                if (kc == 0 || c1 > 32) {
                    bf16x8 afA[4], afB[4], bfr[4];
#pragma unroll
                    for (int nt = 0; nt < 4; ++nt)
                        if (nt * 16 < c2)
                            bfr[nt] = *(const bf16x8*)(W + (nt * 16 + lm) * 64 + kc * 32 + q * 8);
#pragma unroll
                    for (int mt = 0; mt < 4; ++mt) {
                        afA[mt] = *(const bf16x8*)(&sA[((f0a + ky) * 66 + mt * 16 + lm + kx) * SAS + kc * 32 + q * 8]);
                        afB[mt] = *(const bf16x8*)(&sA[((f0b + ky) * 66 + mt * 16 + lm + kx) * SAS + kc * 32 + q * 8]);
                    }
#pragma unroll
                    for (int nt = 0; nt < 4; ++nt)
                        if (nt * 16 < c2)
#pragma unroll
                            for (int mt = 0; mt < 4; ++mt) {
                                accA[mt][nt] = MFMA(bfr[nt], afA[mt], accA[mt][nt], 0, 0, 0);
                                accB[mt][nt] = MFMA(bfr[nt], afB[mt], accB[mt][nt], 0, 0, 0);
                            }
                }
            W += 4096;
        }
}

// 3x3 conv, one row, NORMAL operands (lane: oc=nt*16+lm, px=mt*16+q*4+r)
DI void conv3_nm1(const short* __restrict__ sA, int f0,
                  const short* __restrict__ WB, int c1, int c2,
                  int lm, int q, f32x4 (&acc)[4][4]) {
    const short* __restrict__ W = WB;
#pragma unroll 1
    for (int ky = 0; ky < 3; ++ky)
#pragma unroll 1
        for (int kx = 0; kx < 3; ++kx) {
#pragma unroll
            for (int kc = 0; kc < 2; ++kc)
                if (kc == 0 || c1 > 32) {
                    bf16x8 af[4], bfr[4];
#pragma unroll
                    for (int nt = 0; nt < 4; ++nt)
                        if (nt * 16 < c2)
                            bfr[nt] = *(const bf16x8*)(W + (nt * 16 + lm) * 64 + kc * 32 + q * 8);
#pragma unroll
                    for (int mt = 0; mt < 4; ++mt)
                        af[mt] = *(const bf16x8*)(&sA[((f0 + ky) * 66 + mt * 16 + lm + kx) * SAS + kc * 32 + q * 8]);
#pragma unroll
                    for (int nt = 0; nt < 4; ++nt)
                        if (nt * 16 < c2)
#pragma unroll
                            for (int mt = 0; mt < 4; ++mt)
                                acc[mt][nt] = MFMA(af[mt], bfr[nt], acc[mt][nt], 0, 0, 0);
                }
            W += 4096;
        }
}

// 1x1 conv, swapped, accumulate (input = n1 slot row, col = px+1)
DI void conv1_sw(const short* __restrict__ sRow, const short* __restrict__ W1,
                 int c1, int c2, int lm, int q, f32x4 (&acc)[4][4]) {
#pragma unroll
    for (int kc = 0; kc < 2; ++kc)
        if (kc == 0 || c1 > 32) {
            bf16x8 af[4], bfr[4];
#pragma unroll
            for (int mt = 0; mt < 4; ++mt)
                af[mt] = *(const bf16x8*)(&sRow[(mt * 16 + lm + 1) * SAS + kc * 32 + q * 8]);
#pragma unroll
            for (int nt = 0; nt < 4; ++nt)
                if (nt * 16 < c2)
                    bfr[nt] = *(const bf16x8*)(W1 + (nt * 16 + lm) * 64 + kc * 32 + q * 8);
#pragma unroll
            for (int nt = 0; nt < 4; ++nt)
                if (nt * 16 < c2)
#pragma unroll
                    for (int mt = 0; mt < 4; ++mt)
                        acc[mt][nt] = MFMA(bfr[nt], af[mt], acc[mt][nt], 0, 0, 0);
        }
}

// 1x1 conv, normal, accumulate (input = n2 scratch row, no col halo)
DI void conv1_nm(const short* __restrict__ sRow, const short* __restrict__ W1,
                 int c1, int c2, int lm, int q, f32x4 (&acc)[4][4]) {
#pragma unroll
    for (int kc = 0; kc < 2; ++kc)
        if (kc == 0 || c1 > 32) {
            bf16x8 af[4], bfr[4];
#pragma unroll
            for (int mt = 0; mt < 4; ++mt)
                af[mt] = *(const bf16x8*)(&sRow[(mt * 16 + lm) * SAS + kc * 32 + q * 8]);
#pragma unroll
            for (int nt = 0; nt < 4; ++nt)
                if (nt * 16 < c2)
                    bfr[nt] = *(const bf16x8*)(W1 + (nt * 16 + lm) * 64 + kc * 32 + q * 8);
#pragma unroll
            for (int nt = 0; nt < 4; ++nt)
                if (nt * 16 < c2)
#pragma unroll
                    for (int mt = 0; mt < 4; ++mt)
                        acc[mt][nt] = MFMA(af[mt], bfr[nt], acc[mt][nt], 0, 0, 0);
        }
}

// relu+bias epi from a SWAPPED acc into a [px][stride SAS] row (colOff: 1 for
// frame slots with halo, 0 for n2 scratch). live=false writes zeros.
DI void epi_sw(short* __restrict__ dst, int colOff, const float* __restrict__ b0,
               const float* __restrict__ b1, bool live, int lm, int q,
               const f32x4 (&acc)[4][4]) {
#pragma unroll
    for (int nt = 0; nt < 4; ++nt) {
        const f32x4 bva = *(const f32x4*)(b0 + nt * 16 + q * 4);
        f32x4 bv = bva;
        if (b1) {
            const f32x4 bvb = *(const f32x4*)(b1 + nt * 16 + q * 4);
#pragma unroll
            for (int r = 0; r < 4; ++r) bv[r] += bvb[r];
        }
#pragma unroll
        for (int mt = 0; mt < 4; ++mt) {
            s16x4 pk = (s16x4)0;
            if (live) {
#pragma unroll
                for (int r = 0; r < 4; ++r)
                    pk[r] = f2bf(fmaxf(acc[mt][nt][r] + bv[r], 0.f));
            }
            *(s16x4*)(&dst[(mt * 16 + lm + colOff) * SAS + nt * 16 + q * 4]) = pk;
        }
    }
}

// ---------------------------------------------------------------------------
// Fully fused cell kernel. 512 threads (8 waves), 4 output rows per block.
// LDS frames 0-7 = x rows y0-2..y0+5 (relu'd bf16); after B2 frames alias the
// n1 slots 0-5. n2 scratch + p3 exchange in disjoint LDS regions -> only 4
// barriers and no global round trip for n1/n2/p3.
// Roles: w0-5 -> n1 rows 0-5 (e0, swapped); w6/w7 -> e1 rows {0,1}/{2,3} +
// conv1_e0 -> n2 -> conv1_e1 -> p3; w0-3 -> e2 (normal) + final combine.
// ---------------------------------------------------------------------------
__global__ __launch_bounds__(512, 2) void fused_cell_kernel(
    const float* __restrict__ x, const char* __restrict__ ws,
    float* __restrict__ outp) {
    extern __shared__ __align__(16) short sA[];
    const int t = threadIdx.x, w = t >> 6, l = t & 63, lm = l & 15, q = l >> 4;
    const int y0 = blockIdx.x * 4, n = blockIdx.y;
    const int* cc = (const int*)(ws + OFF_CC);
    const int c1 = __builtin_amdgcn_readfirstlane(cc[0]);
    const int c2 = __builtin_amdgcn_readfirstlane(cc[1]);
    const int SGm = (c1 > 32) ? 8 : 4;
    const float* __restrict__ bias = (const float*)(ws + OFF_BIAS);
    const short* __restrict__ WBe0 = (const short*)(ws + OFF_WB3);
    const short* __restrict__ WBe1 = WBe0 + 36864;
    const short* __restrict__ WBe2 = WBe0 + 2 * 36864;
    const short* __restrict__ W1e0 = (const short*)(ws + OFF_WB1);
    const short* __restrict__ W1e1 = W1e0 + 4096;

    f32x4 accA[4][4], accB[4][4];
#pragma unroll
    for (int i = 0; i < 4; ++i)
#pragma unroll
        for (int j = 0; j < 4; ++j) { accA[i][j] = 0.f; accB[i][j] = 0.f; }

    // ---- P0: stage 8 x frames (fused relu + bf16 + transpose) ----
    if (t < 128) {    // zero halo cols 0,65 of all 8 frames
        const int r = t >> 4, chp = (t >> 3) & 1, sg = t & 7;
        *(bf16x8*)(&sA[(r * 66 + chp * 65) * SAS + sg * 8]) = (bf16x8)0;
    }
    if (w < SGm) {    // wave w stages ic-group w for all 8 rows
#pragma unroll 1
        for (int r = 0; r < 8; ++r) {
            const int gy = y0 + r - 2;
            const float* __restrict__ src = x + (((size_t)n * 64 + w * 8) * 64 + gy) * 64 + l;
            bf16x8 pk = (bf16x8)0;
            if ((unsigned)gy < 64u) {
#pragma unroll
                for (int j = 0; j < 8; ++j)
                    pk[j] = f2bf(fmaxf(src[j * HW], 0.f));
            }
            *(bf16x8*)(&sA[(r * 66 + l + 1) * SAS + w * 8]) = pk;
        }
    }
    __syncthreads();   // B1: frames ready

    // ---- P1: all x-convs ----
    if (w < 6) {
        conv3_sw1(sA, w, WBe0, c1, c2, lm, q, accA);            // n1 row w
    } else if (w == 6) {
        conv3_sw2(sA, 1, 2, WBe1, c1, c2, lm, q, accA, accB);   // e1 out rows 0,1
    } else {
        conv3_sw2(sA, 3, 4, WBe1, c1, c2, lm, q, accA, accB);   // e1 out rows 2,3
    }
    __syncthreads();   // B2: x reads done -> frames become n1 slots

    // ---- n1 epi: rows 0-5 -> slots 0-5 (zero rows outside the image) ----
    if (w < 6) {
        const int gy = y0 - 1 + w;
        epi_sw(&sA[w * FR], 1, bias, nullptr, (unsigned)gy < 64u, lm, q, accA);
    }
    __syncthreads();   // B3: n1 ready

    // ---- P2: e2 (w0-3) and the n2/p3 chain (w6,w7) ----
    if (w < 4) {
        conv3_nm1(sA, w, WBe2, c1, c2, lm, q, accB);            // e2 out row w
    } else if (w >= 6) {
        const int ra = 2 * (w - 6), rb = ra + 1;
        // conv1_e0(n1 same y) accumulates into the e1 accs
        conv1_sw(&sA[(ra + 1) * FR], W1e0, c1, c2, lm, q, accA);
        conv1_sw(&sA[(rb + 1) * FR], W1e0, c1, c2, lm, q, accB);
        // n2 epi -> scratch rows (disjoint region, wave-private)
        epi_sw(&sA[L_N2 + ra * N2R], 0, bias + 64, bias + 128, true, lm, q, accA);
        epi_sw(&sA[L_N2 + rb * N2R], 0, bias + 64, bias + 128, true, lm, q, accB);
        // conv1_e1 (normal order) from scratch; reuse accs
#pragma unroll
        for (int i = 0; i < 4; ++i)
#pragma unroll
            for (int j = 0; j < 4; ++j) { accA[i][j] = 0.f; accB[i][j] = 0.f; }
        conv1_nm(&sA[L_N2 + ra * N2R], W1e1, c1, c2, lm, q, accA);
        conv1_nm(&sA[L_N2 + rb * N2R], W1e1, c1, c2, lm, q, accB);
        // p3 epi (bf16, normal layout [oc][px]) -> exchange region
#pragma unroll
        for (int nt = 0; nt < 4; ++nt) {
            const float bva = bias[256 + nt * 16 + lm];
#pragma unroll
            for (int mt = 0; mt < 4; ++mt) {
                s16x4 pa, pb;
#pragma unroll
                for (int r = 0; r < 4; ++r) {
                    pa[r] = f2bf(accA[mt][nt][r] + bva);
                    pb[r] = f2bf(accB[mt][nt][r] + bva);
                }
                *(s16x4*)(&sA[L_P3 + ra * N2R + (nt * 16 + lm) * SAS + mt * 16 + q * 4]) = pa;
                *(s16x4*)(&sA[L_P3 + rb * N2R + (nt * 16 + lm) * SAS + mt * 16 + q * 4]) = pb;
            }
        }
    }
    __syncthreads();   // B4: e2 + p3 ready

    // ---- P3: combine + coalesced f32x4 store (w0-3 own out rows 0-3) ----
    if (w < 4) {
        const int y = y0 + w;
        const float* __restrict__ bias3 = bias + 192;
#pragma unroll
        for (int nt = 0; nt < 4; ++nt) {
            const int oc = nt * 16 + lm;
            const float bvs = bias3[oc];
#pragma unroll
            for (int mt = 0; mt < 4; ++mt) {
                const s16x4 p = *(const s16x4*)(&sA[L_P3 + w * N2R + oc * SAS + mt * 16 + q * 4]);
                const size_t ob = (((size_t)n * 64 + oc) * 64 + y) * 64 + mt * 16 + q * 4;
                const f32x4 s = *(const f32x4*)(x + ob);   // skip = raw x
                f32x4 v;
#pragma unroll
                for (int r = 0; r < 4; ++r)
                    v[r] = accB[mt][nt][r] + bvs + bf2f(p[r]) + s[r];
                *(f32x4*)(outp + ob) = v;   // oc>=c2: acc=bias=p3=0 -> skip only
            }
        }
    }
}

// ---------------------------------------------------------------------------
extern "C" void kernel_launch(void* const* d_in, const int* in_sizes, int n_in,
                              void* d_out, int out_size, void* d_ws, size_t ws_size,
                              hipStream_t stream) {
    (void)in_sizes; (void)n_in; (void)out_size; (void)ws_size;
    const float* x  = (const float*)d_in[0];
    const float* a1 = (const float*)d_in[1];
    const float* a2 = (const float*)d_in[2];
    const float* w3 = (const float*)d_in[3];
    const float* w1 = (const float*)d_in[4];
    const float* bn = (const float*)d_in[5];
    char* ws = (char*)d_ws;

    static int attr_done = 0;
    if (!attr_done) {
        hipFuncSetAttribute((const void*)fused_cell_kernel,
                            hipFuncAttributeMaxDynamicSharedMemorySize,
                            L_TOT * 2);
        attr_done = 1;
    }

    prep_kernel<<<466, 256, 0, stream>>>(w3, w1, bn, a1, a2, ws);
    const dim3 gc(16, 32);   // y-tiles, n
    fused_cell_kernel<<<gc, 512, L_TOT * 2, stream>>>(x, ws, (float*)d_out);
}